// Round 4
// baseline (564.419 us; speedup 1.0000x reference)
//
#include <hip/hip_runtime.h>
#include <stdint.h>

typedef unsigned __int128 u128;
typedef unsigned long long u64;

#define B 16
#define T 1024
#define V 4096
#define P 100
#define L 128

// Kernel 0: Eq[b][c] = 128-bit mask of label positions j < ll with
// labels[b][j] == c. 1 MB table, L2-resident for the Myers kernel.
__global__ __launch_bounds__(256) void eq_build_kernel(
    const int* __restrict__ labels,
    const int* __restrict__ labels_length,
    ulonglong2* __restrict__ eq)          // (B, V)
{
    __shared__ int lab[L];
    int b = blockIdx.x >> 4;              // 16 blocks of 256 c's per b
    int c = ((blockIdx.x & 15) << 8) | threadIdx.x;
    if (threadIdx.x < L) lab[threadIdx.x] = labels[b * L + threadIdx.x];
    __syncthreads();
    int ll = labels_length[b];            // uniform per block; ll in [64,128]
    u64 lo = 0, hi = 0;
    #pragma unroll
    for (int j = 0; j < 64; j++) lo |= (u64)(lab[j] == c) << j;
    #pragma unroll
    for (int j = 0; j < 64; j++) hi |= (u64)(lab[64 + j] == c) << j;
    if (ll < 128) hi &= (1ull << (ll - 64)) - 1ull;   // mask bits >= ll
    eq[(size_t)b * V + c] = make_ulonglong2(lo, hi);
}

// Kernel 1: partial scores. 4 waves per (b,p); one int4 path read per lane
// -> 4 independent gathers. (log-softmax normalizer cancels in the softmax
// over p, so it is skipped entirely — no need to read all of emissions.)
__global__ __launch_bounds__(256) void scores4_kernel(
    const float* __restrict__ emissions,
    const int* __restrict__ emissions_lengths,
    const int* __restrict__ paths,
    float* __restrict__ scores_part)      // (B*P, 4)
{
    int gid = blockIdx.x * blockDim.x + threadIdx.x;
    int wave = gid >> 6;
    int lane = threadIdx.x & 63;
    if (wave >= B * P * 4) return;
    int w  = wave & 3;
    int bp = wave >> 2;
    int b  = bp / P;
    int len = emissions_lengths[b];
    const int4* path4 = (const int4*)(paths + (size_t)bp * T);
    int4 tk = path4[w * 64 + lane];
    int tbase = 4 * (w * 64 + lane);
    const float* em = emissions + (size_t)b * T * V;

    float acc = 0.f;
    if (tbase + 0 < len) acc += em[(size_t)(tbase + 0) * V + tk.x];
    if (tbase + 1 < len) acc += em[(size_t)(tbase + 1) * V + tk.y];
    if (tbase + 2 < len) acc += em[(size_t)(tbase + 2) * V + tk.z];
    if (tbase + 3 < len) acc += em[(size_t)(tbase + 3) * V + tk.w];

    #pragma unroll
    for (int off = 32; off; off >>= 1) acc += __shfl_down(acc, off, 64);
    if (lane == 0) scores_part[bp * 4 + w] = acc;
}

// Kernel 2: Myers/Hyyro bit-parallel Levenshtein (rapidfuzz recurrence),
// 128-bit pattern in one u128 per lane. One lane per (b,p) problem: ZERO
// cross-lane traffic — the R3 post-mortem showed the diagonal DP's
// shuffle chain is unhideable at ~1 wave/SIMD. CTC-collapse is folded in
// as per-step validity predication (skip update for blank/repeat/masked).
// Eq loads prefetched 4 steps ahead (tokens known in advance).
__global__ __launch_bounds__(64) void wer_myers_kernel(
    const int* __restrict__ emissions_lengths,
    const int* __restrict__ labels_length,
    const int* __restrict__ paths,
    const ulonglong2* __restrict__ eqtab,
    float* __restrict__ wers)
{
    int bp = blockIdx.x * 64 + threadIdx.x;      // exactly 1600 lanes
    int b = bp / P;
    int len = emissions_lengths[b];
    int ll = labels_length[b];                   // in [64,128]
    const int* path = paths + (size_t)bp * T;
    const ulonglong2* eqb = eqtab + (size_t)b * V;

    u128 VP = (ll >= 128) ? ~(u128)0 : (((u128)1 << ll) - 1);
    u128 VN = 0;
    const u128 mbit = (u128)1 << (ll - 1);
    int dist = ll;                               // = D[0][ll]
    int prev = -1;

    auto step = [&](int c, ulonglong2 eqv, int t) {
        bool v = (c != 0) & (c != prev) & (t < len);
        prev = c;
        u128 X  = ((u128)eqv.y << 64) | eqv.x;
        u128 D0 = (((X & VP) + VP) ^ VP) | X | VN;
        u128 HP = VN | ~(D0 | VP);
        u128 HN = D0 & VP;
        int delta = (int)((HP & mbit) != 0) - (int)((HN & mbit) != 0);
        HP = (HP << 1) | 1;
        HN = HN << 1;
        u128 nVP = HN | ~(D0 | HP);
        u128 nVN = HP & D0;
        if (v) { VP = nVP; VN = nVN; dist += delta; }
    };

    // wave-max len (lanes span at most 2 b's), rounded up to 4
    int lmax = len;
    #pragma unroll
    for (int off = 32; off; off >>= 1) lmax = max(lmax, __shfl_xor(lmax, off, 64));
    lmax = (lmax + 3) & ~3;

    int4 tok = *(const int4*)path;
    ulonglong2 e0 = eqb[tok.x], e1 = eqb[tok.y], e2 = eqb[tok.z], e3 = eqb[tok.w];

    for (int t0 = 0; t0 < lmax; t0 += 4) {
        int tn = min(t0 + 4, T - 4);             // clamped in-row prefetch
        int4 ntok = *(const int4*)(path + tn);
        ulonglong2 f0 = eqb[ntok.x], f1 = eqb[ntok.y],
                   f2 = eqb[ntok.z], f3 = eqb[ntok.w];

        step(tok.x, e0, t0 + 0);
        step(tok.y, e1, t0 + 1);
        step(tok.z, e2, t0 + 2);
        step(tok.w, e3, t0 + 3);

        tok = ntok; e0 = f0; e1 = f1; e2 = f2; e3 = f3;
    }
    wers[bp] = (float)dist;
}

// Kernel 3: out = sum_b sum_p softmax_p(scores[b,:])[p] * wers[b,p]
__global__ __launch_bounds__(1024) void reduce_kernel(
    const float* __restrict__ scores_part,        // (B*P, 4)
    const float* __restrict__ wers,
    float* __restrict__ out)
{
    __shared__ float contrib[B];
    int lane = threadIdx.x & 63;
    int b = threadIdx.x >> 6;                     // 16 waves, one per batch

    int p1 = b * P + lane;
    float s1 = scores_part[p1 * 4 + 0] + scores_part[p1 * 4 + 1]
             + scores_part[p1 * 4 + 2] + scores_part[p1 * 4 + 3];
    float w1 = wers[p1];
    bool has2 = lane < (P - 64);
    int p2 = b * P + 64 + (has2 ? lane : 0);
    float s2 = has2 ? (scores_part[p2 * 4 + 0] + scores_part[p2 * 4 + 1]
                     + scores_part[p2 * 4 + 2] + scores_part[p2 * 4 + 3])
                    : -3.4e38f;
    float w2 = has2 ? wers[p2] : 0.f;

    float m = fmaxf(s1, s2);
    #pragma unroll
    for (int off = 32; off; off >>= 1) m = fmaxf(m, __shfl_xor(m, off, 64));
    float e1 = expf(s1 - m);
    float e2 = has2 ? expf(s2 - m) : 0.f;
    float num = e1 * w1 + e2 * w2;
    float den = e1 + e2;
    #pragma unroll
    for (int off = 32; off; off >>= 1) {
        num += __shfl_xor(num, off, 64);
        den += __shfl_xor(den, off, 64);
    }
    if (lane == 0) contrib[b] = num / den;
    __syncthreads();
    if (threadIdx.x == 0) {
        float s = 0.f;
        #pragma unroll
        for (int i = 0; i < B; i++) s += contrib[i];
        out[0] = s;
    }
}

extern "C" void kernel_launch(void* const* d_in, const int* in_sizes, int n_in,
                              void* d_out, int out_size, void* d_ws, size_t ws_size,
                              hipStream_t stream) {
    const float* emissions          = (const float*)d_in[0];
    const int*   emissions_lengths  = (const int*)d_in[1];
    const int*   labels             = (const int*)d_in[2];
    const int*   labels_length      = (const int*)d_in[3];
    const int*   paths              = (const int*)d_in[4];
    float* out = (float*)d_out;

    ulonglong2* eq      = (ulonglong2*)d_ws;              // 1 MB
    float* scores_part  = (float*)((char*)d_ws + (size_t)B * V * 16);
    float* wers         = scores_part + B * P * 4;

    eq_build_kernel<<<B * (V / 256), 256, 0, stream>>>(labels, labels_length, eq);
    scores4_kernel<<<(B * P * 4 * 64) / 256, 256, 0, stream>>>(
        emissions, emissions_lengths, paths, scores_part);
    wer_myers_kernel<<<B * P / 64, 64, 0, stream>>>(
        emissions_lengths, labels_length, paths, eq, wers);
    reduce_kernel<<<1, 1024, 0, stream>>>(scores_part, wers, out);
}